// Round 5
// baseline (65.171 us; speedup 1.0000x reference)
//
#include <hip/hip_runtime.h>

#define N 8192
#define F 128
#define MARGIN 0.2f
#define NEG_FILL_BITS 0x7149f2cau  // bits of 1e30f
#define NINF (-3.0e38f)
#define PINF (3.0e38f)
#define NUM_IDS 512

typedef unsigned short ushort_t;
typedef unsigned int uint_t;
typedef _Float16 half8 __attribute__((ext_vector_type(8)));
typedef float f32x4 __attribute__((ext_vector_type(4)));

// ---------------------------------------------------------------------------
// ws layout (bytes):
//   [0,    4N)        : pos    (uint)  v=1+hard_pos_d2 (float bits), sorted order
//   [4N,   8N)        : neg    (uint)  v=1+hard_neg_d2 (float bits), sorted order
//   [8N,  12N)        : sid    (int)   sorted ids
//   [12N, 12N+2048)   : bincur (int)   bin cursors
//   [12N+4096, +2MB)  : H      (fp16)  [N][128] features, sorted order
//   then EA [N][8] fp16 (A-side ext), EB [N][8] fp16 (B-side ext)
// acc = S - na/2 - nb/2 = -d2/2  (norms folded into MFMA via ext slots)
// ---------------------------------------------------------------------------

__global__ __launch_bounds__(512) void hist_kernel(const int* __restrict__ ids,
                                                   int* __restrict__ bincur) {
    __shared__ int h[NUM_IDS];
    __shared__ int sc[NUM_IDS];
    const int tid = threadIdx.x;
    h[tid] = 0;
    __syncthreads();
#pragma unroll
    for (int i = 0; i < N / NUM_IDS; ++i) atomicAdd(&h[ids[i * NUM_IDS + tid]], 1);
    __syncthreads();
    int v = h[tid];
    sc[tid] = v;
    __syncthreads();
    for (int off = 1; off < NUM_IDS; off <<= 1) {
        int add = (tid >= off) ? sc[tid - off] : 0;
        __syncthreads();
        sc[tid] += add;
        __syncthreads();
    }
    bincur[tid] = sc[tid] - v;  // exclusive prefix = bin start
}

// Counting-sort scatter + fp16 convert + norm ext-slot build + pos/neg init.
__global__ __launch_bounds__(256) void prep_kernel(const float* __restrict__ A,
                                                   const int* __restrict__ ids,
                                                   int* __restrict__ bincur,
                                                   ushort_t* __restrict__ H,
                                                   ushort_t* __restrict__ EA,
                                                   ushort_t* __restrict__ EB,
                                                   uint_t* __restrict__ pos,
                                                   uint_t* __restrict__ neg,
                                                   int* __restrict__ sid) {
    int t = blockIdx.x * 256 + threadIdx.x;  // 0 .. N*32-1
    int row = t >> 5, kg = t & 31;
    int lane = threadIdx.x & 63;
    int id = ids[row];
    float4 v = *reinterpret_cast<const float4*>(A + row * F + kg * 4);
    float f[4] = {v.x, v.y, v.z, v.w};
    ushort4 h;
    {
        _Float16 h0 = (_Float16)f[0], h1 = (_Float16)f[1], h2 = (_Float16)f[2], h3 = (_Float16)f[3];
        __builtin_memcpy(&h.x, &h0, 2);
        __builtin_memcpy(&h.y, &h1, 2);
        __builtin_memcpy(&h.z, &h2, 2);
        __builtin_memcpy(&h.w, &h3, 2);
    }
    float s = fmaf(f[0], f[0], fmaf(f[1], f[1], fmaf(f[2], f[2], f[3] * f[3])));
#pragma unroll
    for (int m = 1; m <= 16; m <<= 1) s += __shfl_xor(s, m, 64);  // 32-lane row groups
    int np = 0;
    if ((lane & 31) == 0) np = atomicAdd(&bincur[id], 1);  // sorted position
    np = __shfl(np, lane & 32, 64);                        // broadcast within row group
    *reinterpret_cast<ushort4*>(H + (size_t)np * F + kg * 4) = h;
    if ((lane & 31) == 0) {
        float hf = 0.5f * s;
        _Float16 nh = (_Float16)hf;
        _Float16 nl = (_Float16)(hf - (float)nh);
        ushort_t uh, ul;
        __builtin_memcpy(&uh, &nh, 2);
        __builtin_memcpy(&ul, &nl, 2);
        uint_t nhn = (uint_t)(uh ^ 0x8000u);  // -na_hi/2
        uint_t nln = (uint_t)(ul ^ 0x8000u);  // -na_lo/2
        const uint_t one2 = 0x3C003C00u;      // [1.0h, 1.0h]
        uint4 ea = make_uint4(one2, nhn | (nln << 16), 0u, 0u);  // [1,1,-nh,-nl,0..]
        uint4 eb = make_uint4(nhn | (nln << 16), one2, 0u, 0u);  // [-nh,-nl,1,1,0..]
        *reinterpret_cast<uint4*>(EA + (size_t)np * 8) = ea;
        *reinterpret_cast<uint4*>(EB + (size_t)np * 8) = eb;
        sid[np] = id;
        pos[np] = 0u;
        neg[np] = NEG_FILL_BITS;
    }
}

#define LOAD_FRAGS(AV, BV, KS)                                                         \
    _Pragma("unroll") for (int m_ = 0; m_ < 4; ++m_) {                                 \
        AV[m_] = *reinterpret_cast<const half8*>(                                      \
            H + (size_t)(rowbase + wr * 64 + m_ * 16 + lr) * F + (KS)*32 + lg * 8);    \
        BV[m_] = *reinterpret_cast<const half8*>(                                      \
            H + (size_t)(colbase + wc * 64 + m_ * 16 + lr) * F + (KS)*32 + lg * 8);    \
    }

#define DO_MFMA(AV, BV)                                                                \
    _Pragma("unroll") for (int m_ = 0; m_ < 4; ++m_)                                   \
        _Pragma("unroll") for (int n_ = 0; n_ < 4; ++n_)                               \
            acc[m_][n_] = __builtin_amdgcn_mfma_f32_16x16x32_f16(AV[m_], BV[n_],       \
                                                                 acc[m_][n_], 0, 0, 0);

// One 128x128 upper-triangular tile per block; direct global->register frags,
// no LDS staging, no barriers in the compute path. acc = -d2/2.
__global__ __launch_bounds__(256, 2) void hard_mine_mfma(const ushort_t* __restrict__ H,
                                                         const ushort_t* __restrict__ EA,
                                                         const ushort_t* __restrict__ EB,
                                                         const int* __restrict__ sid,
                                                         uint_t* __restrict__ pos,
                                                         uint_t* __restrict__ neg) {
    __shared__ uint_t ls_rp[128], ls_rn[128], ls_cp[128], ls_cn[128];

    const int tid = threadIdx.x;
    const int w = tid >> 6, lane = tid & 63;
    const int wr = w >> 1, wc = w & 1;  // wave's 64x64 quadrant
    const int lr = lane & 15, lg = lane >> 4;

    int t = blockIdx.x;
    int bj = (int)((sqrtf(8.0f * (float)t + 1.0f) - 1.0f) * 0.5f);
    while ((bj + 1) * (bj + 2) / 2 <= t) ++bj;
    while (bj * (bj + 1) / 2 > t) --bj;
    const int bi = t - bj * (bj + 1) / 2;
    const int rowbase = bi * 128;
    const int colbase = bj * 128;
    const bool shared_ids = (bi == bj) || (sid[rowbase + 127] == sid[colbase]);

    if (tid < 128) {
        ls_rp[tid] = 0u;
        ls_cp[tid] = 0u;
        ls_rn[tid] = NEG_FILL_BITS;
        ls_cn[tid] = NEG_FILL_BITS;
    }

    // ---- fragment loads: all independent, issued up front ----
    half8 a0[4], b0[4], a1[4], b1[4], a2[4], b2[4], a3[4], b3[4], ae[4], be[4];
    LOAD_FRAGS(a0, b0, 0)
    LOAD_FRAGS(a1, b1, 1)
    LOAD_FRAGS(a2, b2, 2)
    LOAD_FRAGS(a3, b3, 3)
    {
        half8 z8 = {};
#pragma unroll
        for (int m = 0; m < 4; ++m) {
            ae[m] = (lg == 0) ? *reinterpret_cast<const half8*>(
                                    EA + (size_t)(rowbase + wr * 64 + m * 16 + lr) * 8)
                              : z8;
            be[m] = (lg == 0) ? *reinterpret_cast<const half8*>(
                                    EB + (size_t)(colbase + wc * 64 + m * 16 + lr) * 8)
                              : z8;
        }
    }

    f32x4 acc[4][4];
#pragma unroll
    for (int m = 0; m < 4; ++m)
#pragma unroll
        for (int n = 0; n < 4; ++n)
            acc[m][n] = (f32x4)0.0f;

    DO_MFMA(a0, b0)
    DO_MFMA(a1, b1)
    DO_MFMA(a2, b2)
    DO_MFMA(a3, b3)
    DO_MFMA(ae, be)  // adds -na/2 - nb/2  ->  acc = -d2/2

    if (!shared_ids) {
        // ---- fast path: all pairs differ -> neg = -2*max(acc). Pure max folds.
        float rmx[4][4], cmx[4];
#pragma unroll
        for (int m = 0; m < 4; ++m)
#pragma unroll
            for (int q = 0; q < 4; ++q) {
                float x = fmaxf(fmaxf(acc[m][0][q], acc[m][1][q]), acc[m][2][q]);
                rmx[m][q] = fmaxf(x, acc[m][3][q]);
            }
#pragma unroll
        for (int n = 0; n < 4; ++n) {
            float c = fmaxf(fmaxf(acc[0][n][0], acc[0][n][1]),
                            fmaxf(acc[0][n][2], acc[0][n][3]));
#pragma unroll
            for (int m = 1; m < 4; ++m) {
                c = fmaxf(c, fmaxf(fmaxf(acc[m][n][0], acc[m][n][1]),
                                   fmaxf(acc[m][n][2], acc[m][n][3])));
            }
            cmx[n] = c;
        }
#pragma unroll
        for (int mk = 1; mk < 16; mk <<= 1)
#pragma unroll
            for (int m = 0; m < 4; ++m)
#pragma unroll
                for (int q = 0; q < 4; ++q)
                    rmx[m][q] = fmaxf(rmx[m][q], __shfl_xor(rmx[m][q], mk, 64));
#pragma unroll
        for (int mk = 16; mk < 64; mk <<= 1)
#pragma unroll
            for (int n = 0; n < 4; ++n)
                cmx[n] = fmaxf(cmx[n], __shfl_xor(cmx[n], mk, 64));

        __syncthreads();  // ls init visible
        if (lr == 0) {
#pragma unroll
            for (int m = 0; m < 4; ++m)
#pragma unroll
                for (int q = 0; q < 4; ++q) {
                    int rl = wr * 64 + m * 16 + lg * 4 + q;
                    float vv = fmaf(-2.0f, rmx[m][q], 1.0f);  // 1 + d2_min >= ~1
                    atomicMin(&ls_rn[rl], __float_as_uint(vv));
                }
        }
        if (lane < 16) {
#pragma unroll
            for (int n = 0; n < 4; ++n) {
                int cl = wc * 64 + n * 16 + lane;
                float vv = fmaf(-2.0f, cmx[n], 1.0f);
                atomicMin(&ls_cn[cl], __float_as_uint(vv));
            }
        }
        __syncthreads();
        if (tid < 128) {
            atomicMin(&neg[rowbase + tid], ls_rn[tid]);
            atomicMin(&neg[colbase + tid], ls_cn[tid]);
        }
    } else {
        // ---- general path: per-element id compare; pos = -2*min_same(acc),
        //      neg = -2*max_diff(acc). Shared cndmask feeds row+col minings.
        int myid[4][4], jd[4];
#pragma unroll
        for (int m = 0; m < 4; ++m) {
            int4 v4 = *reinterpret_cast<const int4*>(sid + rowbase + wr * 64 + m * 16 + lg * 4);
            myid[m][0] = v4.x; myid[m][1] = v4.y; myid[m][2] = v4.z; myid[m][3] = v4.w;
        }
#pragma unroll
        for (int n = 0; n < 4; ++n) jd[n] = sid[colbase + wc * 64 + n * 16 + lr];

        float pmn[4][4], rmx[4][4], cpm[4], cmx[4];
#pragma unroll
        for (int m = 0; m < 4; ++m)
#pragma unroll
            for (int q = 0; q < 4; ++q) {
                pmn[m][q] = PINF;
                rmx[m][q] = NINF;
            }
#pragma unroll
        for (int n = 0; n < 4; ++n) {
            cpm[n] = PINF;
            cmx[n] = NINF;
        }
#pragma unroll
        for (int n = 0; n < 4; ++n) {
            const int jdv = jd[n];
#pragma unroll
            for (int m = 0; m < 4; ++m)
#pragma unroll
                for (int q = 0; q < 4; ++q) {
                    float a = acc[m][n][q];
                    bool same = (jdv == myid[m][q]);
                    float tp = same ? a : PINF;
                    float tn = same ? NINF : a;
                    pmn[m][q] = fminf(pmn[m][q], tp);
                    rmx[m][q] = fmaxf(rmx[m][q], tn);
                    cpm[n] = fminf(cpm[n], tp);
                    cmx[n] = fmaxf(cmx[n], tn);
                }
        }
#pragma unroll
        for (int mk = 1; mk < 16; mk <<= 1)
#pragma unroll
            for (int m = 0; m < 4; ++m)
#pragma unroll
                for (int q = 0; q < 4; ++q) {
                    pmn[m][q] = fminf(pmn[m][q], __shfl_xor(pmn[m][q], mk, 64));
                    rmx[m][q] = fmaxf(rmx[m][q], __shfl_xor(rmx[m][q], mk, 64));
                }
#pragma unroll
        for (int mk = 16; mk < 64; mk <<= 1)
#pragma unroll
            for (int n = 0; n < 4; ++n) {
                cpm[n] = fminf(cpm[n], __shfl_xor(cpm[n], mk, 64));
                cmx[n] = fmaxf(cmx[n], __shfl_xor(cmx[n], mk, 64));
            }

        __syncthreads();
        if (lr == 0) {
#pragma unroll
            for (int m = 0; m < 4; ++m)
#pragma unroll
                for (int q = 0; q < 4; ++q) {
                    int rl = wr * 64 + m * 16 + lg * 4 + q;
                    float vp = fmaxf(fmaf(-2.0f, pmn[m][q], 1.0f), 0.0f);  // -INF->0 neutral
                    float vn = fmaf(-2.0f, rmx[m][q], 1.0f);               // NINF->huge, neutral
                    atomicMax(&ls_rp[rl], __float_as_uint(vp));
                    atomicMin(&ls_rn[rl], __float_as_uint(vn));
                }
        }
        if (lane < 16) {
#pragma unroll
            for (int n = 0; n < 4; ++n) {
                int cl = wc * 64 + n * 16 + lane;
                float vp = fmaxf(fmaf(-2.0f, cpm[n], 1.0f), 0.0f);
                float vn = fmaf(-2.0f, cmx[n], 1.0f);
                atomicMax(&ls_cp[cl], __float_as_uint(vp));
                atomicMin(&ls_cn[cl], __float_as_uint(vn));
            }
        }
        __syncthreads();
        if (tid < 128) {
            atomicMax(&pos[rowbase + tid], ls_rp[tid]);
            atomicMin(&neg[rowbase + tid], ls_rn[tid]);
            atomicMax(&pos[colbase + tid], ls_cp[tid]);
            atomicMin(&neg[colbase + tid], ls_cn[tid]);
        }
    }
}

// Fused row-loss + reduction: one block, 1024 threads, 8 rows each.
__global__ __launch_bounds__(1024) void finish_kernel(const uint_t* __restrict__ pos,
                                                      const uint_t* __restrict__ neg,
                                                      float* __restrict__ out) {
    float s = 0.0f;
#pragma unroll
    for (int i = 0; i < N / 1024; ++i) {
        int r = threadIdx.x + i * 1024;
        float vp = __uint_as_float(pos[r]);
        float vn = __uint_as_float(neg[r]);  // 1e30 if no negatives -> loss 0
        float hp = sqrtf(fmaxf(vp - 1.0f, 0.0f) + 1e-12f);
        float hn = sqrtf(fmaxf(vn - 1.0f, 0.0f) + 1e-12f);
        s += fmaxf(MARGIN + hp - hn, 0.0f);
    }
#pragma unroll
    for (int m = 32; m >= 1; m >>= 1) s += __shfl_xor(s, m, 64);
    __shared__ float wsum[16];
    int lane = threadIdx.x & 63;
    int wave = threadIdx.x >> 6;
    if (lane == 0) wsum[wave] = s;
    __syncthreads();
    if (threadIdx.x == 0) {
        float v = 0.0f;
#pragma unroll
        for (int k = 0; k < 16; ++k) v += wsum[k];
        out[0] = v * (1.0f / (float)N);  // LOSS_FACTOR == 1
    }
}

extern "C" void kernel_launch(void* const* d_in, const int* in_sizes, int n_in,
                              void* d_out, int out_size, void* d_ws, size_t ws_size,
                              hipStream_t stream) {
    (void)in_sizes; (void)n_in; (void)out_size; (void)ws_size;
    const float* A = (const float*)d_in[0];
    const int* ids = (const int*)d_in[1];
    float* out = (float*)d_out;

    char* ws = (char*)d_ws;
    uint_t* pos = (uint_t*)ws;
    uint_t* neg = (uint_t*)(ws + 4 * N);
    int* sid = (int*)(ws + 8 * N);
    int* bincur = (int*)(ws + 12 * N);
    ushort_t* H = (ushort_t*)(ws + 12 * N + 4096);
    ushort_t* EA = H + (size_t)N * F;      // [N][8]
    ushort_t* EB = EA + (size_t)N * 8;     // [N][8]

    hist_kernel<<<1, 512, 0, stream>>>(ids, bincur);
    prep_kernel<<<N * 32 / 256, 256, 0, stream>>>(A, ids, bincur, H, EA, EB, pos, neg, sid);
    hard_mine_mfma<<<64 * 65 / 2, 256, 0, stream>>>(H, EA, EB, sid, pos, neg);
    finish_kernel<<<1, 1024, 0, stream>>>(pos, neg, out);
}